// Round 10
// baseline (197.521 us; speedup 1.0000x reference)
//
#include <hip/hip_runtime.h>

#define R   256
#define S   128
#define CM  256
#define CH  32
#define CZ  128

typedef __attribute__((ext_vector_type(8))) short short8;
typedef __attribute__((ext_vector_type(4))) float f32x4;
typedef __attribute__((ext_vector_type(16))) float f32x16;
typedef unsigned short ushort_t;

__device__ inline ushort_t f2bf(float f) {
    union { float f; unsigned u; } v; v.f = f;
    unsigned u = v.u;
    unsigned r = u + 0x7FFF + ((u >> 16) & 1);
    return (ushort_t)(r >> 16);
}

// ---------------------------------------------------------------------------
// K1 (merged): LN+proj (blocks [0,512)), scale (blocks [512,1536)),
// WTp transpose (blocks [1536,1664)). Verbatim R5 (passed four times).
// ---------------------------------------------------------------------------
__global__ __launch_bounds__(256) void k_lnproj(
    const float* __restrict__ m, const float* __restrict__ mask,
    const float* __restrict__ g, const float* __restrict__ beta,
    const float* __restrict__ b1, const float* __restrict__ b2,
    const float* __restrict__ w1, const float* __restrict__ w2,
    const float* __restrict__ w_out,
    ushort_t* __restrict__ Abig, ushort_t* __restrict__ BbigT,
    float* __restrict__ scale, ushort_t* __restrict__ WTp) {
    __shared__ ushort_t mnL[64 * CM];      // 32 KB (aliased by scale branch)
    int t = threadIdx.x;
    int b = blockIdx.x;

    if (b >= 1536) {                       // ---- WTp transpose ----
        int z = b - 1536;
        #pragma unroll
        for (int q = 0; q < 4; ++q) {
            int k2 = q * 256 + t;
            int e = k2 >> 5, c = k2 & 31;
            WTp[(size_t)z * 1024 + k2] = f2bf(w_out[(size_t)(c * 32 + e) * CZ + z]);
        }
        return;
    }
    if (b >= 512) {                        // ---- scale ----
        float* red = (float*)mnL;          // [4][64]
        int bb = b - 512;
        int i = bb >> 2, jq = bb & 3;
        int jl = t & 63, wv = t >> 6;
        int j = jq * 64 + jl;
        const float* mi = mask + (size_t)(wv * 32) * R + i;
        const float* mj = mask + (size_t)(wv * 32) * R + j;
        float acc = 0.f;
        #pragma unroll
        for (int s = 0; s < 32; ++s) acc += mi[s * R] * mj[s * R];
        red[wv * 64 + jl] = acc;
        __syncthreads();
        if (t < 64) {
            float v = red[t] + red[64 + t] + red[128 + t] + red[192 + t];
            scale[(size_t)i * R + jq * 64 + t] = 1.0f / (1e-3f + v);
        }
        return;
    }

    // ---- LN + projections ----
    int sg = b & 7, rg = b >> 3;
    int s0 = sg * 16, r0 = rg * 4;

    int ml = t >> 2, part = t & 3;
    int r_l = ml >> 4, s_l = ml & 15;
    size_t p = (size_t)(s0 + s_l) * R + (r0 + r_l);
    const float4* row = (const float4*)(m + p * CM + part * 64);
    float4 x[16];
    float sum = 0.f, sq = 0.f;
    #pragma unroll
    for (int i = 0; i < 16; ++i) {
        x[i] = row[i];
        sum += x[i].x + x[i].y + x[i].z + x[i].w;
        sq  += x[i].x * x[i].x + x[i].y * x[i].y
             + x[i].z * x[i].z + x[i].w * x[i].w;
    }
    sum += __shfl_xor(sum, 1); sum += __shfl_xor(sum, 2);
    sq  += __shfl_xor(sq, 1);  sq  += __shfl_xor(sq, 2);
    float mean = sum * (1.0f / CM);
    float var  = sq * (1.0f / CM) - mean * mean;
    float inv  = rsqrtf(var + 1e-5f);
    const float4* g4 = (const float4*)(g + part * 64);
    const float4* be4 = (const float4*)(beta + part * 64);
    #pragma unroll
    for (int c8 = 0; c8 < 8; ++c8) {
        float4 a = x[2 * c8], bq = x[2 * c8 + 1];
        float4 ga = g4[2 * c8], gb = g4[2 * c8 + 1];
        float4 ba = be4[2 * c8], bb = be4[2 * c8 + 1];
        union { ushort_t u[8]; uint4 v; } pk;
        pk.u[0] = f2bf((a.x - mean) * inv * ga.x + ba.x);
        pk.u[1] = f2bf((a.y - mean) * inv * ga.y + ba.y);
        pk.u[2] = f2bf((a.z - mean) * inv * ga.z + ba.z);
        pk.u[3] = f2bf((a.w - mean) * inv * ga.w + ba.w);
        pk.u[4] = f2bf((bq.x - mean) * inv * gb.x + bb.x);
        pk.u[5] = f2bf((bq.y - mean) * inv * gb.y + bb.y);
        pk.u[6] = f2bf((bq.z - mean) * inv * gb.z + bb.z);
        pk.u[7] = f2bf((bq.w - mean) * inv * gb.w + bb.w);
        int ck = part * 8 + c8;
        int phys = ck ^ (ml & 15);
        *(uint4*)&mnL[ml * CM + phys * 8] = pk.v;
    }

    // W fragments: direct gather from w1/w2 (column ch, stride CH floats).
    int w = t >> 6, lane = t & 63, quad = lane >> 4, l15 = lane & 15;
    int ch = w * 16 + l15;
    const float* wsrc = (ch < CH) ? w1 : w2;
    int cidx = ch & 31;
    short8 bfrs[8];
    #pragma unroll
    for (int ks = 0; ks < 8; ++ks) {
        int cb = ks * 4 + quad;
        union { ushort_t u[8]; short8 v; } pw;
        #pragma unroll
        for (int e = 0; e < 8; ++e)
            pw.u[e] = f2bf(wsrc[(size_t)(cb * 8 + e) * CH + cidx]);
        bfrs[ks] = pw.v;
    }
    __syncthreads();

    f32x4 acc[4];
    #pragma unroll
    for (int a = 0; a < 4; a++) acc[a] = (f32x4)(0.f);
    #pragma unroll
    for (int ks = 0; ks < 8; ++ks) {
        int cb = ks * 4 + quad;
        #pragma unroll
        for (int mt = 0; mt < 4; ++mt) {
            int mm = mt * 16 + l15;
            short8 afr = *(const short8*)&mnL[mm * CM + ((cb ^ l15) << 3)];
            acc[mt] = __builtin_amdgcn_mfma_f32_16x16x32_bf16(afr, bfrs[ks], acc[mt], 0, 0, 0);
        }
    }

    float bias = (ch < CH) ? b1[cidx] : b2[cidx];
    ushort_t* dst = (ch < CH) ? Abig : BbigT;
    #pragma unroll
    for (int mt = 0; mt < 4; ++mt) {
        int r = r0 + mt;
        union { ushort_t u[4]; uint2 v; } pk;
        #pragma unroll
        for (int reg = 0; reg < 4; ++reg) {
            int s = s0 + quad * 4 + reg;
            float mv = mask[(size_t)s * R + r];
            pk.u[reg] = f2bf((acc[mt][reg] + bias) * mv);
        }
        *(uint2*)&dst[((size_t)r * CH + cidx) * S + s0 + quad * 4] = pk.v;
    }
}

// ---------------------------------------------------------------------------
// K2: R8's verified 2-phase skeleton + stage-1 + pack byte-identical.
// NEW: stage-2 uses 32x32x16 MFMA. Per-instr: same 16B/lane A-read but
// 32K flop -> per-flop LDS cost halved; of-reads 128->64 per wave-tile
// (total LDS reads 192->128). W:MFMA stays 1:1 per 32K-flop instr, batched
// 4-per-strip (k_lnproj bfrs-style, proven to pipeline). Wave = pair-half
// (ph=w>>2, 32 pairs) x z-quarter (zq=w&3, 32 z); single f32x16 acc.
// A-frag layout: row=lane&31, k=(lane>>5)*8 (lane-width analog of the
// verified 16x16x32 usage); C/D: col=lane&31, row=(reg&3)+8*(reg>>2)+
// 4*(lane>>5) (guide, m74/m101-verified). Epilogue now 128B-coalesced.
// ---------------------------------------------------------------------------
__global__ __launch_bounds__(512, 4) void k_fuse(
    const ushort_t* __restrict__ Abig, const ushort_t* __restrict__ BbigT,
    const ushort_t* __restrict__ WTp, const float* __restrict__ b_out,
    const float* __restrict__ scale, float* __restrict__ out) {
    __shared__ ushort_t oc2[64 * 512];       // 64 KB, 4-bit swizzled
    __shared__ ushort_t shB[2][32 * 128];    // 2 x 8 KB
    int t = threadIdx.x;
    int w = t >> 6, lane = t & 63, quad = lane >> 4, l15 = lane & 15;
    int l31 = lane & 31, lhi = lane >> 5;
    int ib = blockIdx.x >> 5, jb = blockIdx.x & 31;
    int i_g = ib * 8 + w;
    int jj = l15 & 7, elb = l15 >> 3;

    // A-frags for this wave's i-strip (register-resident, coalesced loads)
    short8 af[2][4];
    #pragma unroll
    for (int mt = 0; mt < 2; ++mt)
        #pragma unroll
        for (int ks = 0; ks < 4; ++ks)
            af[mt][ks] = *(const short8*)
                &Abig[((size_t)i_g * 32 + mt * 16 + l15) * S + ks * 32 + quad * 8];

    // B staging: thread t owns LDS row r2 = t>>4 (0..31), 16B chunk ck = t&15
    int r2 = t >> 4, ck = t & 15;
    const ushort_t* gB = BbigT
        + ((size_t)jb * 256 + (r2 & 7) * 32 + (r2 >> 3)) * S + ck * 8;
    ushort_t* bdst[2];
    bdst[0] = &shB[0][r2 * 128 + ((ck ^ (r2 & 15)) << 3)];
    bdst[1] = &shB[1][r2 * 128 + ((ck ^ (r2 & 15)) << 3)];
    uint4 breg = *(const uint4*)&gB[0];      // prefetch ec=0

    // stage-2: wave = (pair-half ph = w>>2) x (z-quarter zq = w&3), 32x32 MFMA
    int ph = w >> 2, zq = w & 3;
    const ushort_t* Wp = WTp + ((size_t)(zq * 32) + l31) * 1024 + lhi * 8;
    int ocrow = ph * 32 + l31;               // oc pair-row this lane reads
    int pwr = w * 8 + jj;                    // oc pair-row this lane writes

    f32x16 acc2 = (f32x16)(0.f);

    for (int phase = 0; phase < 2; ++phase) {
        // ---- stage-1 phase: 4 ec chunks, shB barriers only (R8 verbatim) ----
        #pragma unroll
        for (int e2 = 0; e2 < 4; ++e2) {
            int ec = phase * 4 + e2;
            int buf = ec & 1;
            *(uint4*)bdst[buf] = breg;
            if (ec < 7) breg = *(const uint4*)&gB[(ec + 1) * 512];
            __syncthreads();   // publish shB[buf]; (e2==0) also closes
                               // previous phase's stage-2 oc reads

            f32x4 acc1[2][2];
            #pragma unroll
            for (int a = 0; a < 2; a++)
                #pragma unroll
                for (int bq = 0; bq < 2; bq++) acc1[a][bq] = (f32x4)(0.f);
            #pragma unroll
            for (int ks = 0; ks < 4; ++ks) {
                int chq = ks * 4 + quad;
                int r20 = elb * 8 + jj;      // nt=0: e = ec*4 + elb
                int r21 = r20 + 16;          // nt=1: e = ec*4 + 2 + elb
                short8 bf0 = *(const short8*)
                    &shB[buf][r20 * 128 + ((chq ^ (r20 & 15)) << 3)];
                short8 bf1 = *(const short8*)
                    &shB[buf][r21 * 128 + ((chq ^ (r21 & 15)) << 3)];
                #pragma unroll
                for (int mt = 0; mt < 2; ++mt) {
                    acc1[mt][0] = __builtin_amdgcn_mfma_f32_16x16x32_bf16(
                        af[mt][ks], bf0, acc1[mt][0], 0, 0, 0);
                    acc1[mt][1] = __builtin_amdgcn_mfma_f32_16x16x32_bf16(
                        af[mt][ks], bf1, acc1[mt][1], 0, 0, 0);
                }
            }
            // pack to oc2: row pwr, phase-local slot = e2*16 + k2l/8; 4-bit swz
            #pragma unroll
            for (int mt = 0; mt < 2; ++mt) {
                int c00 = mt * 16 + quad * 4;
                #pragma unroll
                for (int nt = 0; nt < 2; ++nt) {
                    int el = nt * 2 + elb;
                    int k2l = el * 32 + c00;
                    int slot = e2 * 16 + (k2l >> 3);
                    union { ushort_t u[4]; uint2 v; } pk;
                    #pragma unroll
                    for (int reg = 0; reg < 4; ++reg)
                        pk.u[reg] = f2bf(acc1[mt][nt][reg]);
                    *(uint2*)((char*)oc2 + pwr * 1024
                              + ((slot ^ (pwr & 15)) << 4)
                              + ((k2l & 7) << 1)) = pk.v;
                }
            }
        }
        __syncthreads();   // publish oc2 for this phase

        // ---- stage-2 phase: 32 K-steps of 32x32x16, zero barriers ----
        // strip-mined by 4: batch 4 W loads + 4 of reads, then 4 MFMAs
        for (int ks4 = 0; ks4 < 8; ++ks4) {
            short8 wfs[4], ofs[4];
            #pragma unroll
            for (int u = 0; u < 4; ++u) {
                int kst = ks4 * 4 + u;                   // phase-local step
                wfs[u] = *(const short8*)&Wp[(phase * 32 + kst) * 16];
                int slot = kst * 2 + lhi;
                ofs[u] = *(const short8*)
                    ((const char*)oc2 + ocrow * 1024 + ((slot ^ (ocrow & 15)) << 4));
            }
            #pragma unroll
            for (int u = 0; u < 4; ++u)
                acc2 = __builtin_amdgcn_mfma_f32_32x32x16_bf16(
                    ofs[u], wfs[u], acc2, 0, 0, 0);
        }
    }

    // ---- epilogue: bias + 1/(eps+norm) scale; 128B-coalesced stores ----
    float bz = b_out[zq * 32 + l31];
    #pragma unroll
    for (int rg2 = 0; rg2 < 16; ++rg2) {
        int mrow = (rg2 & 3) + 8 * (rg2 >> 2) + 4 * lhi;
        int pq = ph * 32 + mrow;
        int pg = (ib * 8 + (pq >> 3)) * R + jb * 8 + (pq & 7);
        out[(size_t)pg * CZ + zq * 32 + l31] = (acc2[rg2] + bz) * scale[pg];
    }
}

// ---------------------------------------------------------------------------
extern "C" void kernel_launch(void* const* d_in, const int* in_sizes, int n_in,
                              void* d_out, int out_size, void* d_ws, size_t ws_size,
                              hipStream_t stream) {
    const float* m    = (const float*)d_in[0];
    const float* mask = (const float*)d_in[1];
    const float* g    = (const float*)d_in[2];
    const float* be   = (const float*)d_in[3];
    const float* w1   = (const float*)d_in[4];
    const float* b1   = (const float*)d_in[5];
    const float* w2   = (const float*)d_in[6];
    const float* b2   = (const float*)d_in[7];
    const float* wo   = (const float*)d_in[8];
    const float* bo   = (const float*)d_in[9];
    float* out = (float*)d_out;

    char* ws = (char*)d_ws;
    ushort_t* Abig  = (ushort_t*)ws;                        // 2 MB
    ushort_t* BbigT = Abig + (size_t)R * CH * S;            // 2 MB
    ushort_t* WTp   = BbigT + (size_t)R * CH * S;           // 256 KB
    float*    scale = (float*)(WTp + (size_t)CZ * CH * CH); // 256 KB

    k_lnproj<<<1664, 256, 0, stream>>>(m, mask, g, be, b1, b2, w1, w2, wo,
                                       Abig, BbigT, scale, WTp);
    k_fuse<<<1024, 512, 0, stream>>>(Abig, BbigT, WTp, bo, scale, out);
}

// Round 11
// 156.372 us; speedup vs baseline: 1.2631x; 1.2631x over previous
//
#include <hip/hip_runtime.h>

#define R   256
#define S   128
#define CM  256
#define CH  32
#define CZ  128

typedef __attribute__((ext_vector_type(8))) short short8;
typedef __attribute__((ext_vector_type(4))) float f32x4;
typedef unsigned short ushort_t;

__device__ inline ushort_t f2bf(float f) {
    union { float f; unsigned u; } v; v.f = f;
    unsigned u = v.u;
    unsigned r = u + 0x7FFF + ((u >> 16) & 1);
    return (ushort_t)(r >> 16);
}

// ---------------------------------------------------------------------------
// K1 (merged): LN+proj (blocks [0,512)), scale (blocks [512,1536)),
// WTp transpose (blocks [1536,1664)). Verbatim R5 (best-measured config).
// ---------------------------------------------------------------------------
__global__ __launch_bounds__(256) void k_lnproj(
    const float* __restrict__ m, const float* __restrict__ mask,
    const float* __restrict__ g, const float* __restrict__ beta,
    const float* __restrict__ b1, const float* __restrict__ b2,
    const float* __restrict__ w1, const float* __restrict__ w2,
    const float* __restrict__ w_out,
    ushort_t* __restrict__ Abig, ushort_t* __restrict__ BbigT,
    float* __restrict__ scale, ushort_t* __restrict__ WTp) {
    __shared__ ushort_t mnL[64 * CM];      // 32 KB (aliased by scale branch)
    int t = threadIdx.x;
    int b = blockIdx.x;

    if (b >= 1536) {                       // ---- WTp transpose ----
        int z = b - 1536;
        #pragma unroll
        for (int q = 0; q < 4; ++q) {
            int k2 = q * 256 + t;
            int e = k2 >> 5, c = k2 & 31;
            WTp[(size_t)z * 1024 + k2] = f2bf(w_out[(size_t)(c * 32 + e) * CZ + z]);
        }
        return;
    }
    if (b >= 512) {                        // ---- scale ----
        float* red = (float*)mnL;          // [4][64]
        int bb = b - 512;
        int i = bb >> 2, jq = bb & 3;
        int jl = t & 63, wv = t >> 6;
        int j = jq * 64 + jl;
        const float* mi = mask + (size_t)(wv * 32) * R + i;
        const float* mj = mask + (size_t)(wv * 32) * R + j;
        float acc = 0.f;
        #pragma unroll
        for (int s = 0; s < 32; ++s) acc += mi[s * R] * mj[s * R];
        red[wv * 64 + jl] = acc;
        __syncthreads();
        if (t < 64) {
            float v = red[t] + red[64 + t] + red[128 + t] + red[192 + t];
            scale[(size_t)i * R + jq * 64 + t] = 1.0f / (1e-3f + v);
        }
        return;
    }

    // ---- LN + projections ----
    int sg = b & 7, rg = b >> 3;
    int s0 = sg * 16, r0 = rg * 4;

    int ml = t >> 2, part = t & 3;
    int r_l = ml >> 4, s_l = ml & 15;
    size_t p = (size_t)(s0 + s_l) * R + (r0 + r_l);
    const float4* row = (const float4*)(m + p * CM + part * 64);
    float4 x[16];
    float sum = 0.f, sq = 0.f;
    #pragma unroll
    for (int i = 0; i < 16; ++i) {
        x[i] = row[i];
        sum += x[i].x + x[i].y + x[i].z + x[i].w;
        sq  += x[i].x * x[i].x + x[i].y * x[i].y
             + x[i].z * x[i].z + x[i].w * x[i].w;
    }
    sum += __shfl_xor(sum, 1); sum += __shfl_xor(sum, 2);
    sq  += __shfl_xor(sq, 1);  sq  += __shfl_xor(sq, 2);
    float mean = sum * (1.0f / CM);
    float var  = sq * (1.0f / CM) - mean * mean;
    float inv  = rsqrtf(var + 1e-5f);
    const float4* g4 = (const float4*)(g + part * 64);
    const float4* be4 = (const float4*)(beta + part * 64);
    #pragma unroll
    for (int c8 = 0; c8 < 8; ++c8) {
        float4 a = x[2 * c8], bq = x[2 * c8 + 1];
        float4 ga = g4[2 * c8], gb = g4[2 * c8 + 1];
        float4 ba = be4[2 * c8], bb = be4[2 * c8 + 1];
        union { ushort_t u[8]; uint4 v; } pk;
        pk.u[0] = f2bf((a.x - mean) * inv * ga.x + ba.x);
        pk.u[1] = f2bf((a.y - mean) * inv * ga.y + ba.y);
        pk.u[2] = f2bf((a.z - mean) * inv * ga.z + ba.z);
        pk.u[3] = f2bf((a.w - mean) * inv * ga.w + ba.w);
        pk.u[4] = f2bf((bq.x - mean) * inv * gb.x + bb.x);
        pk.u[5] = f2bf((bq.y - mean) * inv * gb.y + bb.y);
        pk.u[6] = f2bf((bq.z - mean) * inv * gb.z + bb.z);
        pk.u[7] = f2bf((bq.w - mean) * inv * gb.w + bb.w);
        int ck = part * 8 + c8;
        int phys = ck ^ (ml & 15);
        *(uint4*)&mnL[ml * CM + phys * 8] = pk.v;
    }

    // W fragments: direct gather from w1/w2 (column ch, stride CH floats).
    // 64 scalar L2 loads/lane, issued here so they overlap the barrier.
    int w = t >> 6, lane = t & 63, quad = lane >> 4, l15 = lane & 15;
    int ch = w * 16 + l15;
    const float* wsrc = (ch < CH) ? w1 : w2;
    int cidx = ch & 31;
    short8 bfrs[8];
    #pragma unroll
    for (int ks = 0; ks < 8; ++ks) {
        int cb = ks * 4 + quad;
        union { ushort_t u[8]; short8 v; } pw;
        #pragma unroll
        for (int e = 0; e < 8; ++e)
            pw.u[e] = f2bf(wsrc[(size_t)(cb * 8 + e) * CH + cidx]);
        bfrs[ks] = pw.v;
    }
    __syncthreads();

    f32x4 acc[4];
    #pragma unroll
    for (int a = 0; a < 4; a++) acc[a] = (f32x4)(0.f);
    #pragma unroll
    for (int ks = 0; ks < 8; ++ks) {
        int cb = ks * 4 + quad;
        #pragma unroll
        for (int mt = 0; mt < 4; ++mt) {
            int mm = mt * 16 + l15;
            short8 afr = *(const short8*)&mnL[mm * CM + ((cb ^ l15) << 3)];
            acc[mt] = __builtin_amdgcn_mfma_f32_16x16x32_bf16(afr, bfrs[ks], acc[mt], 0, 0, 0);
        }
    }

    float bias = (ch < CH) ? b1[cidx] : b2[cidx];
    ushort_t* dst = (ch < CH) ? Abig : BbigT;
    #pragma unroll
    for (int mt = 0; mt < 4; ++mt) {
        int r = r0 + mt;
        union { ushort_t u[4]; uint2 v; } pk;
        #pragma unroll
        for (int reg = 0; reg < 4; ++reg) {
            int s = s0 + quad * 4 + reg;
            float mv = mask[(size_t)s * R + r];
            pk.u[reg] = f2bf((acc[mt][reg] + bias) * mv);
        }
        *(uint2*)&dst[((size_t)r * CH + cidx) * S + s0 + quad * 4] = pk.v;
    }
}

// ---------------------------------------------------------------------------
// K2: FUSED outer-product + projection — EXACT R0 structure (best measured
// across 4 sessions: 54.4/55.6/61.4/55.0 us). Two barriers per iter,
// single-buffered oc, double-buffered shB, W loaded inline in stage-2 with
// 1:4 amortization. Six restructuring attempts (barriers, conflicts,
// occupancy, traffic rebalance, 32x32 MFMA) all regressed or were neutral —
// this is the structure's floor; do not modify without a new counter signal.
// ---------------------------------------------------------------------------
__global__ __launch_bounds__(512, 4) void k_fuse(
    const ushort_t* __restrict__ Abig, const ushort_t* __restrict__ BbigT,
    const ushort_t* __restrict__ WTp, const float* __restrict__ b_out,
    const float* __restrict__ scale, float* __restrict__ out) {
    __shared__ ushort_t oc[64 * 128];        // 16 KB
    __shared__ ushort_t shB[2][32 * 128];    // 2 x 8 KB, [el*8+j][s] swizzled
    int t = threadIdx.x;
    int w = t >> 6, lane = t & 63, quad = lane >> 4, l15 = lane & 15;
    int ib = blockIdx.x >> 5, jb = blockIdx.x & 31;
    int i_g = ib * 8 + w;
    int jj = l15 & 7, elb = l15 >> 3;

    // A-frags for this wave's i-strip (register-resident, coalesced loads)
    short8 af[2][4];
    #pragma unroll
    for (int mt = 0; mt < 2; ++mt)
        #pragma unroll
        for (int ks = 0; ks < 4; ++ks)
            af[mt][ks] = *(const short8*)
                &Abig[((size_t)i_g * 32 + mt * 16 + l15) * S + ks * 32 + quad * 8];

    // B staging: thread t owns LDS row r2 = t>>4 (0..31), 16B chunk ck = t&15
    // global row = jb*256 + (r2&7)*32 + ec*4 + (r2>>3)
    int r2 = t >> 4, ck = t & 15;
    const ushort_t* gB = BbigT
        + ((size_t)jb * 256 + (r2 & 7) * 32 + (r2 >> 3)) * S + ck * 8;
    ushort_t* bdst[2];
    bdst[0] = &shB[0][r2 * 128 + ((ck ^ (r2 & 15)) << 3)];
    bdst[1] = &shB[1][r2 * 128 + ((ck ^ (r2 & 15)) << 3)];
    uint4 breg = *(const uint4*)&gB[0];      // prefetch ec=0 (e += 4 <=> +512)

    const ushort_t* Wp = WTp + (size_t)(w * 16 + l15) * 1024 + quad * 8;
    int pwr = w * 8 + jj;                    // oc pair-row this lane writes

    f32x4 acc2[4];
    #pragma unroll
    for (int pt = 0; pt < 4; ++pt) acc2[pt] = (f32x4)(0.f);

    for (int ec = 0; ec < 8; ++ec) {
        int buf = ec & 1;
        *(uint4*)bdst[buf] = breg;
        if (ec < 7) breg = *(const uint4*)&gB[(ec + 1) * 512];
        __syncthreads();   // publishes shB[buf]; closes prev stage-2 oc reads

        // ---- stage-1: OC chunk (e = ec*4 .. ec*4+3) ----
        f32x4 acc1[2][2];
        #pragma unroll
        for (int a = 0; a < 2; a++)
            #pragma unroll
            for (int b = 0; b < 2; b++) acc1[a][b] = (f32x4)(0.f);
        #pragma unroll
        for (int ks = 0; ks < 4; ++ks) {
            int chq = ks * 4 + quad;
            int r20 = elb * 8 + jj;          // nt=0: e = ec*4 + elb
            int r21 = r20 + 16;              // nt=1: e = ec*4 + 2 + elb
            short8 bf0 = *(const short8*)
                &shB[buf][r20 * 128 + ((chq ^ (r20 & 15)) << 3)];
            short8 bf1 = *(const short8*)
                &shB[buf][r21 * 128 + ((chq ^ (r21 & 15)) << 3)];
            #pragma unroll
            for (int mt = 0; mt < 2; ++mt) {
                acc1[mt][0] = __builtin_amdgcn_mfma_f32_16x16x32_bf16(
                    af[mt][ks], bf0, acc1[mt][0], 0, 0, 0);
                acc1[mt][1] = __builtin_amdgcn_mfma_f32_16x16x32_bf16(
                    af[mt][ks], bf1, acc1[mt][1], 0, 0, 0);
            }
        }
        // pack to oc: lane's 4 regs = 4 consecutive c at (pair pwr, e)
        #pragma unroll
        for (int mt = 0; mt < 2; ++mt) {
            int c00 = mt * 16 + quad * 4;
            #pragma unroll
            for (int nt = 0; nt < 2; ++nt) {
                int el = nt * 2 + elb;
                int k2l = el * 32 + c00;
                int cc = k2l >> 3;
                union { ushort_t u[4]; uint2 v; } pk;
                #pragma unroll
                for (int reg = 0; reg < 4; ++reg)
                    pk.u[reg] = f2bf(acc1[mt][nt][reg]);
                *(uint2*)((char*)oc + pwr * 256 + ((cc ^ (pwr & 7)) << 4)
                          + ((k2l & 7) << 1)) = pk.v;
            }
        }
        __syncthreads();   // publishes oc
        // ---- stage-2: out += OC_chunk x WTp_chunk (wave owns 16 z) ----
        #pragma unroll
        for (int ksl = 0; ksl < 4; ++ksl) {
            short8 wf = *(const short8*)&Wp[ec * 128 + ksl * 32];
            #pragma unroll
            for (int pt = 0; pt < 4; ++pt) {
                int pp = pt * 16 + l15;
                int cc = ksl * 4 + quad;
                short8 of = *(const short8*)
                    ((const char*)oc + pp * 256 + ((cc ^ (pp & 7)) << 4));
                acc2[pt] = __builtin_amdgcn_mfma_f32_16x16x32_bf16(
                    of, wf, acc2[pt], 0, 0, 0);
            }
        }
    }

    // ---- epilogue: bias + 1/(eps+norm) scale ----
    float bz = b_out[w * 16 + l15];
    #pragma unroll
    for (int pt = 0; pt < 4; ++pt) {
        #pragma unroll
        for (int reg = 0; reg < 4; ++reg) {
            int pp = pt * 16 + quad * 4 + reg;
            int pg = (ib * 8 + (pp >> 3)) * R + jb * 8 + (pp & 7);
            out[(size_t)pg * CZ + w * 16 + l15] = (acc2[pt][reg] + bz) * scale[pg];
        }
    }
}

// ---------------------------------------------------------------------------
extern "C" void kernel_launch(void* const* d_in, const int* in_sizes, int n_in,
                              void* d_out, int out_size, void* d_ws, size_t ws_size,
                              hipStream_t stream) {
    const float* m    = (const float*)d_in[0];
    const float* mask = (const float*)d_in[1];
    const float* g    = (const float*)d_in[2];
    const float* be   = (const float*)d_in[3];
    const float* w1   = (const float*)d_in[4];
    const float* b1   = (const float*)d_in[5];
    const float* w2   = (const float*)d_in[6];
    const float* b2   = (const float*)d_in[7];
    const float* wo   = (const float*)d_in[8];
    const float* bo   = (const float*)d_in[9];
    float* out = (float*)d_out;

    char* ws = (char*)d_ws;
    ushort_t* Abig  = (ushort_t*)ws;                        // 2 MB
    ushort_t* BbigT = Abig + (size_t)R * CH * S;            // 2 MB
    ushort_t* WTp   = BbigT + (size_t)R * CH * S;           // 256 KB
    float*    scale = (float*)(WTp + (size_t)CZ * CH * CH); // 256 KB

    k_lnproj<<<1664, 256, 0, stream>>>(m, mask, g, be, b1, b2, w1, w2, wo,
                                       Abig, BbigT, scale, WTp);
    k_fuse<<<1024, 512, 0, stream>>>(Abig, BbigT, WTp, bo, scale, out);
}

// Round 12
// 149.971 us; speedup vs baseline: 1.3171x; 1.0427x over previous
//
#include <hip/hip_runtime.h>

#define R   256
#define S   128
#define CM  256
#define CH  32
#define CZ  128

typedef __attribute__((ext_vector_type(8))) short short8;
typedef __attribute__((ext_vector_type(4))) float f32x4;
typedef unsigned short ushort_t;

__device__ inline ushort_t f2bf(float f) {
    union { float f; unsigned u; } v; v.f = f;
    unsigned u = v.u;
    unsigned r = u + 0x7FFF + ((u >> 16) & 1);
    return (ushort_t)(r >> 16);
}

// ---------------------------------------------------------------------------
// K1 (merged): LN+proj (blocks [0,512)), scale (blocks [512,1536)),
// WTp transpose (blocks [1536,1664)).
// Change this round (LN branch only): fully-coalesced m-load — one row per
// wave-instruction (lane l holds floats l*4..+3), 16 rows batched in regs.
// Was: 64 lanes spread over 16 rows x 4 parts = 64 line-requests/instr.
// Now: 16 line-requests/instr, every byte consumed at issue. LN reduce via
// 6-level shfl_xor; g/beta one float4/lane hoisted. mnL layout, MFMA read,
// W-gather, stores: byte-identical to R11.
// ---------------------------------------------------------------------------
__global__ __launch_bounds__(256) void k_lnproj(
    const float* __restrict__ m, const float* __restrict__ mask,
    const float* __restrict__ g, const float* __restrict__ beta,
    const float* __restrict__ b1, const float* __restrict__ b2,
    const float* __restrict__ w1, const float* __restrict__ w2,
    const float* __restrict__ w_out,
    ushort_t* __restrict__ Abig, ushort_t* __restrict__ BbigT,
    float* __restrict__ scale, ushort_t* __restrict__ WTp) {
    __shared__ ushort_t mnL[64 * CM];      // 32 KB (aliased by scale branch)
    int t = threadIdx.x;
    int b = blockIdx.x;

    if (b >= 1536) {                       // ---- WTp transpose ----
        int z = b - 1536;
        #pragma unroll
        for (int q = 0; q < 4; ++q) {
            int k2 = q * 256 + t;
            int e = k2 >> 5, c = k2 & 31;
            WTp[(size_t)z * 1024 + k2] = f2bf(w_out[(size_t)(c * 32 + e) * CZ + z]);
        }
        return;
    }
    if (b >= 512) {                        // ---- scale ----
        float* red = (float*)mnL;          // [4][64]
        int bb = b - 512;
        int i = bb >> 2, jq = bb & 3;
        int jl = t & 63, wv = t >> 6;
        int j = jq * 64 + jl;
        const float* mi = mask + (size_t)(wv * 32) * R + i;
        const float* mj = mask + (size_t)(wv * 32) * R + j;
        float acc = 0.f;
        #pragma unroll
        for (int s = 0; s < 32; ++s) acc += mi[s * R] * mj[s * R];
        red[wv * 64 + jl] = acc;
        __syncthreads();
        if (t < 64) {
            float v = red[t] + red[64 + t] + red[128 + t] + red[192 + t];
            scale[(size_t)i * R + jq * 64 + t] = 1.0f / (1e-3f + v);
        }
        return;
    }

    // ---- LN + projections ----
    int sg = b & 7, rg = b >> 3;
    int s0 = sg * 16, r0 = rg * 4;
    int w = t >> 6, lane = t & 63, quad = lane >> 4, l15 = lane & 15;

    // Coalesced batch load: wave w owns rows ml = w*16 .. w*16+15.
    // Per row, lane holds floats lane*4..lane*4+3 -> one 1KB load/row/wave.
    float4 xr[16];
    #pragma unroll
    for (int i = 0; i < 16; ++i) {
        int ml = w * 16 + i;
        int r_l = ml >> 4, s_l = ml & 15;
        size_t p = (size_t)(s0 + s_l) * R + (r0 + r_l);
        xr[i] = *(const float4*)(m + p * CM + lane * 4);
    }
    float4 gv = *(const float4*)(g + lane * 4);
    float4 bv = *(const float4*)(beta + lane * 4);

    #pragma unroll
    for (int i = 0; i < 16; ++i) {
        int ml = w * 16 + i;
        float4 a = xr[i];
        float s1 = a.x + a.y + a.z + a.w;
        float s2 = a.x * a.x + a.y * a.y + a.z * a.z + a.w * a.w;
        #pragma unroll
        for (int d = 1; d < 64; d <<= 1) {
            s1 += __shfl_xor(s1, d);
            s2 += __shfl_xor(s2, d);
        }
        float mean = s1 * (1.0f / CM);
        float var  = s2 * (1.0f / CM) - mean * mean;
        float inv  = rsqrtf(var + 1e-5f);
        union { ushort_t u[4]; uint2 v; } pk;
        pk.u[0] = f2bf((a.x - mean) * inv * gv.x + bv.x);
        pk.u[1] = f2bf((a.y - mean) * inv * gv.y + bv.y);
        pk.u[2] = f2bf((a.z - mean) * inv * gv.z + bv.z);
        pk.u[3] = f2bf((a.w - mean) * inv * gv.w + bv.w);
        // lane covers logical chunk ck = lane>>1, half (lane&1); same swizzle
        int ck = lane >> 1;
        int phys = ck ^ (ml & 15);
        *(uint2*)&mnL[ml * CM + phys * 8 + (lane & 1) * 4] = pk.v;
    }

    // W fragments: direct gather from w1/w2 (column ch, stride CH floats).
    int ch = w * 16 + l15;
    const float* wsrc = (ch < CH) ? w1 : w2;
    int cidx = ch & 31;
    short8 bfrs[8];
    #pragma unroll
    for (int ks = 0; ks < 8; ++ks) {
        int cb = ks * 4 + quad;
        union { ushort_t u[8]; short8 v; } pw;
        #pragma unroll
        for (int e = 0; e < 8; ++e)
            pw.u[e] = f2bf(wsrc[(size_t)(cb * 8 + e) * CH + cidx]);
        bfrs[ks] = pw.v;
    }
    __syncthreads();

    f32x4 acc[4];
    #pragma unroll
    for (int a = 0; a < 4; a++) acc[a] = (f32x4)(0.f);
    #pragma unroll
    for (int ks = 0; ks < 8; ++ks) {
        int cb = ks * 4 + quad;
        #pragma unroll
        for (int mt = 0; mt < 4; ++mt) {
            int mm = mt * 16 + l15;
            short8 afr = *(const short8*)&mnL[mm * CM + ((cb ^ l15) << 3)];
            acc[mt] = __builtin_amdgcn_mfma_f32_16x16x32_bf16(afr, bfrs[ks], acc[mt], 0, 0, 0);
        }
    }

    float bias = (ch < CH) ? b1[cidx] : b2[cidx];
    ushort_t* dst = (ch < CH) ? Abig : BbigT;
    #pragma unroll
    for (int mt = 0; mt < 4; ++mt) {
        int r = r0 + mt;
        union { ushort_t u[4]; uint2 v; } pk;
        #pragma unroll
        for (int reg = 0; reg < 4; ++reg) {
            int s = s0 + quad * 4 + reg;
            float mv = mask[(size_t)s * R + r];
            pk.u[reg] = f2bf((acc[mt][reg] + bias) * mv);
        }
        *(uint2*)&dst[((size_t)r * CH + cidx) * S + s0 + quad * 4] = pk.v;
    }
}

// ---------------------------------------------------------------------------
// K2: FUSED outer-product + projection — EXACT R0 structure (best measured
// across 5 sessions: 54.4/55.6/61.4/55.0/55.0 us). Two barriers per iter,
// single-buffered oc, double-buffered shB, W loaded inline in stage-2 with
// 1:4 amortization. Six restructuring attempts all regressed or neutral —
// structural floor; do not modify without a new counter signal.
// ---------------------------------------------------------------------------
__global__ __launch_bounds__(512, 4) void k_fuse(
    const ushort_t* __restrict__ Abig, const ushort_t* __restrict__ BbigT,
    const ushort_t* __restrict__ WTp, const float* __restrict__ b_out,
    const float* __restrict__ scale, float* __restrict__ out) {
    __shared__ ushort_t oc[64 * 128];        // 16 KB
    __shared__ ushort_t shB[2][32 * 128];    // 2 x 8 KB, [el*8+j][s] swizzled
    int t = threadIdx.x;
    int w = t >> 6, lane = t & 63, quad = lane >> 4, l15 = lane & 15;
    int ib = blockIdx.x >> 5, jb = blockIdx.x & 31;
    int i_g = ib * 8 + w;
    int jj = l15 & 7, elb = l15 >> 3;

    // A-frags for this wave's i-strip (register-resident, coalesced loads)
    short8 af[2][4];
    #pragma unroll
    for (int mt = 0; mt < 2; ++mt)
        #pragma unroll
        for (int ks = 0; ks < 4; ++ks)
            af[mt][ks] = *(const short8*)
                &Abig[((size_t)i_g * 32 + mt * 16 + l15) * S + ks * 32 + quad * 8];

    // B staging: thread t owns LDS row r2 = t>>4 (0..31), 16B chunk ck = t&15
    // global row = jb*256 + (r2&7)*32 + ec*4 + (r2>>3)
    int r2 = t >> 4, ck = t & 15;
    const ushort_t* gB = BbigT
        + ((size_t)jb * 256 + (r2 & 7) * 32 + (r2 >> 3)) * S + ck * 8;
    ushort_t* bdst[2];
    bdst[0] = &shB[0][r2 * 128 + ((ck ^ (r2 & 15)) << 3)];
    bdst[1] = &shB[1][r2 * 128 + ((ck ^ (r2 & 15)) << 3)];
    uint4 breg = *(const uint4*)&gB[0];      // prefetch ec=0 (e += 4 <=> +512)

    const ushort_t* Wp = WTp + (size_t)(w * 16 + l15) * 1024 + quad * 8;
    int pwr = w * 8 + jj;                    // oc pair-row this lane writes

    f32x4 acc2[4];
    #pragma unroll
    for (int pt = 0; pt < 4; ++pt) acc2[pt] = (f32x4)(0.f);

    for (int ec = 0; ec < 8; ++ec) {
        int buf = ec & 1;
        *(uint4*)bdst[buf] = breg;
        if (ec < 7) breg = *(const uint4*)&gB[(ec + 1) * 512];
        __syncthreads();   // publishes shB[buf]; closes prev stage-2 oc reads

        // ---- stage-1: OC chunk (e = ec*4 .. ec*4+3) ----
        f32x4 acc1[2][2];
        #pragma unroll
        for (int a = 0; a < 2; a++)
            #pragma unroll
            for (int b = 0; b < 2; b++) acc1[a][b] = (f32x4)(0.f);
        #pragma unroll
        for (int ks = 0; ks < 4; ++ks) {
            int chq = ks * 4 + quad;
            int r20 = elb * 8 + jj;          // nt=0: e = ec*4 + elb
            int r21 = r20 + 16;              // nt=1: e = ec*4 + 2 + elb
            short8 bf0 = *(const short8*)
                &shB[buf][r20 * 128 + ((chq ^ (r20 & 15)) << 3)];
            short8 bf1 = *(const short8*)
                &shB[buf][r21 * 128 + ((chq ^ (r21 & 15)) << 3)];
            #pragma unroll
            for (int mt = 0; mt < 2; ++mt) {
                acc1[mt][0] = __builtin_amdgcn_mfma_f32_16x16x32_bf16(
                    af[mt][ks], bf0, acc1[mt][0], 0, 0, 0);
                acc1[mt][1] = __builtin_amdgcn_mfma_f32_16x16x32_bf16(
                    af[mt][ks], bf1, acc1[mt][1], 0, 0, 0);
            }
        }
        // pack to oc: lane's 4 regs = 4 consecutive c at (pair pwr, e)
        #pragma unroll
        for (int mt = 0; mt < 2; ++mt) {
            int c00 = mt * 16 + quad * 4;
            #pragma unroll
            for (int nt = 0; nt < 2; ++nt) {
                int el = nt * 2 + elb;
                int k2l = el * 32 + c00;
                int cc = k2l >> 3;
                union { ushort_t u[4]; uint2 v; } pk;
                #pragma unroll
                for (int reg = 0; reg < 4; ++reg)
                    pk.u[reg] = f2bf(acc1[mt][nt][reg]);
                *(uint2*)((char*)oc + pwr * 256 + ((cc ^ (pwr & 7)) << 4)
                          + ((k2l & 7) << 1)) = pk.v;
            }
        }
        __syncthreads();   // publishes oc
        // ---- stage-2: out += OC_chunk x WTp_chunk (wave owns 16 z) ----
        #pragma unroll
        for (int ksl = 0; ksl < 4; ++ksl) {
            short8 wf = *(const short8*)&Wp[ec * 128 + ksl * 32];
            #pragma unroll
            for (int pt = 0; pt < 4; ++pt) {
                int pp = pt * 16 + l15;
                int cc = ksl * 4 + quad;
                short8 of = *(const short8*)
                    ((const char*)oc + pp * 256 + ((cc ^ (pp & 7)) << 4));
                acc2[pt] = __builtin_amdgcn_mfma_f32_16x16x32_bf16(
                    of, wf, acc2[pt], 0, 0, 0);
            }
        }
    }

    // ---- epilogue: bias + 1/(eps+norm) scale ----
    float bz = b_out[w * 16 + l15];
    #pragma unroll
    for (int pt = 0; pt < 4; ++pt) {
        #pragma unroll
        for (int reg = 0; reg < 4; ++reg) {
            int pp = pt * 16 + quad * 4 + reg;
            int pg = (ib * 8 + (pp >> 3)) * R + jb * 8 + (pp & 7);
            out[(size_t)pg * CZ + w * 16 + l15] = (acc2[pt][reg] + bz) * scale[pg];
        }
    }
}

// ---------------------------------------------------------------------------
extern "C" void kernel_launch(void* const* d_in, const int* in_sizes, int n_in,
                              void* d_out, int out_size, void* d_ws, size_t ws_size,
                              hipStream_t stream) {
    const float* m    = (const float*)d_in[0];
    const float* mask = (const float*)d_in[1];
    const float* g    = (const float*)d_in[2];
    const float* be   = (const float*)d_in[3];
    const float* w1   = (const float*)d_in[4];
    const float* b1   = (const float*)d_in[5];
    const float* w2   = (const float*)d_in[6];
    const float* b2   = (const float*)d_in[7];
    const float* wo   = (const float*)d_in[8];
    const float* bo   = (const float*)d_in[9];
    float* out = (float*)d_out;

    char* ws = (char*)d_ws;
    ushort_t* Abig  = (ushort_t*)ws;                        // 2 MB
    ushort_t* BbigT = Abig + (size_t)R * CH * S;            // 2 MB
    ushort_t* WTp   = BbigT + (size_t)R * CH * S;           // 256 KB
    float*    scale = (float*)(WTp + (size_t)CZ * CH * CH); // 256 KB

    k_lnproj<<<1664, 256, 0, stream>>>(m, mask, g, be, b1, b2, w1, w2, wo,
                                       Abig, BbigT, scale, WTp);
    k_fuse<<<1024, 512, 0, stream>>>(Abig, BbigT, WTp, bo, scale, out);
}